// Round 9
// baseline (161.145 us; speedup 1.0000x reference)
//
#include <hip/hip_runtime.h>

#define NRBF 20
#define FOUT 16
#define NA 768
#define NB 4
#define TPW 12           // tiles per wave (48 tiles / 4 waves)

// Round-12: R10 verbatim, ONE variable changed -- store cache-policy bits.
//
// Ledger: compute amount (R6), store width (R7), full-line coverage (R10),
// chain depth (R9), occupancy (R4), chip-wide write ordering (R11) -- all
// falsified; kernel pinned ~62us vs 24us write floor while rocclr's fill
// streams 6.5 TB/s through the same memory system. Remaining difference:
// plain stores are WRITE-BACK + L2-ALLOCATE -- each XCD pushes ~19MB through
// its 4MB L2, so every line is handled twice (allocate, then victim-evict)
// and eviction machinery caps streaming write BW. sc1 (system-scope) + nt
// writes through/past L2 in one pass -- the plausible fill trick. R7 tested
// only the nt hint (still allocates); sc1 is untested.
//
// Implementation: inline-asm global_store_dwordx4 with sc0 sc1 nt. asm
// volatile WITHOUT a "memory" clobber: nothing reads out[], store operands
// are SSA values, and omitting the clobber lets the compiler keep the 4-deep
// tile pipeline (R8 showed what serializing against the stores costs). The
// compiler can't see these stores, so it won't emit the pre-endpgm drain:
// one explicit s_waitcnt vmcnt(0) at kernel end guarantees completion before
// the dispatch retires.
//
// Everything else bit-identical to R10 (best: 155.2): zero-LDS, phase-split,
// gauge k=(l>>4)*8+j frags, W-side zero-pad, swapped-operand MFMA, raw
// v_sqrt, telescoped recurrence, bias as C-in, 4x ds_bpermute dense-store
// permute (lane l <- lane ((l&3)<<4)|(l>>2) -> lane stores dwords 4l..4l+3).

typedef _Float16 f16x8 __attribute__((ext_vector_type(8)));
typedef float    f32x4 __attribute__((ext_vector_type(4)));

__global__ __launch_bounds__(256, 6) void cfconv_kernel(
    const float* __restrict__ coords,  // [NB, NA, 3] fp32
    const float* __restrict__ Ww,      // [FOUT, NRBF] fp32
    const float* __restrict__ Wb,      // [FOUT] fp32
    float* __restrict__ out)           // [NB, NA, NA, FOUT] fp32
{
    const int tid = threadIdx.x;
    const int n   = blockIdx.x;
    const int b   = blockIdx.y;

    const int w  = tid >> 6;   // wave id 0..3 -> owns tiles w*12 .. w*12+11
    const int l  = tid & 63;
    const int mi = l & 15;     // m sub-index (B col / D col)
    const int g  = l >> 4;     // k-group; lane's D rows are f = 4g+0..3

    const float* cb = coords + (size_t)b * NA * 3;

    // A fragment = W[f = mi][k = 8g+j], zero-padded k >= 20 (L2-hot loads)
    f16x8 afrag;
    #pragma unroll
    for (int j = 0; j < 8; ++j) {
        const int k = g * 8 + j;
        afrag[j] = (k < NRBF) ? (_Float16)Ww[mi * NRBF + k] : (_Float16)0.0f;
    }
    // C-in rows are f = 4g+r -> bias per reg
    const f32x4 cinit = { Wb[4*g+0], Wb[4*g+1], Wb[4*g+2], Wb[4*g+3] };

    const float xn = cb[n*3+0];   // block-uniform -> scalar loads
    const float yn = cb[n*3+1];
    const float zn = cb[n*3+2];

    // Phase 1: all 12 distances as independent chains (coords L2/L3-hot).
    float dv[TPW];
    #pragma unroll
    for (int tt = 0; tt < TPW; ++tt) {
        const int m = (w * TPW + tt) * 16 + mi;
        const float dx = xn - cb[m*3+0];
        const float dy = yn - cb[m*3+1];
        const float dz = zn - cb[m*3+2];
        dv[tt] = __builtin_amdgcn_sqrtf(fmaf(dx, dx, fmaf(dy, dy, dz * dz)));
    }

    const float mu0  = 0.1f * (8 * g);          // segment-start mu
    const float tcst = 0.2f * (8 * g) + 0.1f;   // t_{k0+1} exponent offset
    const float u    = 0.81873075308f;          // e^{-0.2}

    // dense-store permute source lane (validated R8/R10)
    const int srcLane = ((l & 3) << 4) | (l >> 2);
    // lane's dense slot: tile base + l*16B (validated R8/R10)
    float* obase = out + (((size_t)b * NA + n) * NA) * FOUT + l * 4;

    // Phase 2: 12 independent {exp, recurrence, MFMA, permute, store} chains
    #pragma unroll 4
    for (int tt = 0; tt < TPW; ++tt) {
        const int t = w * TPW + tt;
        const float d  = dv[tt];
        const float dd = d - mu0;
        float r = __expf(-10.0f * dd * dd);     // r_{k0}
        float q = __expf(2.0f * d - tcst);      // ratio t_{k0+1}

        f16x8 bfrag;                            // B[k = 8g+j][m = mi]
        bfrag[0] = (_Float16)r;
        #pragma unroll
        for (int j = 1; j < 8; ++j) {
            r *= q;                             // r_{k0+j}
            q *= u;
            bfrag[j] = (_Float16)r;
        }

        f32x4 acc =                             // D = W * RBF^T + bias
            __builtin_amdgcn_mfma_f32_16x16x32_f16(afrag, bfrag, cinit, 0, 0, 0);

        // permute to lane-dense layout (only lgkm ops in the kernel)
        f32x4 sv;
        sv[0] = __shfl(acc[0], srcLane);
        sv[1] = __shfl(acc[1], srcLane);
        sv[2] = __shfl(acc[2], srcLane);
        sv[3] = __shfl(acc[3], srcLane);

        // dense store, WRITE-THROUGH/PAST L2: sc0 sc1 nt (the single change)
        float* p = obase + (size_t)t * 16 * FOUT;
        asm volatile("global_store_dwordx4 %0, %1, off sc0 sc1 nt"
                     :: "v"(p), "v"(sv));
    }

    // compiler can't see the asm stores -> explicit drain before endpgm
    asm volatile("s_waitcnt vmcnt(0)");
}

extern "C" void kernel_launch(void* const* d_in, const int* in_sizes, int n_in,
                              void* d_out, int out_size, void* d_ws, size_t ws_size,
                              hipStream_t stream) {
    const float* coords = (const float*)d_in[0];
    const float* Ww     = (const float*)d_in[1];
    const float* Wb     = (const float*)d_in[2];
    float* out          = (float*)d_out;

    dim3 grid(NA, NB);   // (n, b)
    cfconv_kernel<<<grid, 256, 0, stream>>>(coords, Ww, Wb, out);
}

// Round 10
// 156.725 us; speedup vs baseline: 1.0282x; 1.0282x over previous
//
#include <hip/hip_runtime.h>

#define NRBF 20
#define FOUT 16
#define NA 768
#define NB 4
#define TPW 6            // tiles per wave (half-row blocks: 24 tiles / 4 waves)

// Round-13: MORE waves, SHORTER per-wave chains (the untested inverse of R6).
//
// Ledger: compute amount (R6: fewer waves, same per-wave work -> +9% SLOWER),
// store width (R7), full-line coverage (R10), write ordering (R11), cache
// policy (R12: sc1 bypass -> worse; forced end-drain -> worse), VGPR/SGPR
// occupancy remap (R4), in-wave ILP (R9: -4us). R6 is the only point on the
// wave-count axis and it says we're under-waved. This round doubles the wave
// count: 24576 waves x 6 tiles (vs 12288 x 12). Each wave's serial body and
// store tail halve; 24 blocks/CU in 4 resident rounds overlap one round's
// store tail with the next round's compute head. Bonus: dv[6] + unroll-3
// working set (~80 VGPR est.) now genuinely fits the (256,6) 84-VGPR cap --
// R10's dv[12]+unroll-4 (~110 est.) likely SPILLED to scratch, an invisible
// global-memory tax consistent with the unexplained ~30us.
//
// Value-producing code bit-identical to R10 (best, 155.2): zero-LDS,
// phase-split, gauge k=(l>>4)*8+j frags, W-side zero-pad, swapped-operand
// MFMA (D = W*RBF^T), raw v_sqrt, telescoped recurrence, bias as C-in,
// 4x ds_bpermute dense-store permute, plain dwordx4 stores, NO end drain.

typedef _Float16 f16x8 __attribute__((ext_vector_type(8)));
typedef float    f32x4 __attribute__((ext_vector_type(4)));

__global__ __launch_bounds__(256, 6) void cfconv_kernel(
    const float* __restrict__ coords,  // [NB, NA, 3] fp32
    const float* __restrict__ Ww,      // [FOUT, NRBF] fp32
    const float* __restrict__ Wb,      // [FOUT] fp32
    float* __restrict__ out)           // [NB, NA, NA, FOUT] fp32
{
    const int tid  = threadIdx.x;
    const int i    = blockIdx.x;       // 0..1535
    const int n    = i >> 1;           // output row
    const int half = i & 1;            // which half of the 48 tiles
    const int b    = blockIdx.y;

    const int w  = tid >> 6;   // wave id 0..3
    const int l  = tid & 63;
    const int mi = l & 15;     // m sub-index (B col / D col)
    const int g  = l >> 4;     // k-group; lane's D rows are f = 4g+0..3

    const int t0 = half * 24 + w * TPW;   // this wave's 6 consecutive tiles

    const float* cb = coords + (size_t)b * NA * 3;

    // A fragment = W[f = mi][k = 8g+j], zero-padded k >= 20 (L2-hot loads)
    f16x8 afrag;
    #pragma unroll
    for (int j = 0; j < 8; ++j) {
        const int k = g * 8 + j;
        afrag[j] = (k < NRBF) ? (_Float16)Ww[mi * NRBF + k] : (_Float16)0.0f;
    }
    // C-in rows are f = 4g+r -> bias per reg
    const f32x4 cinit = { Wb[4*g+0], Wb[4*g+1], Wb[4*g+2], Wb[4*g+3] };

    const float xn = cb[n*3+0];   // block-uniform -> scalar loads
    const float yn = cb[n*3+1];
    const float zn = cb[n*3+2];

    // Phase 1: 6 independent distance chains (coords L1/L2-hot)
    float dv[TPW];
    #pragma unroll
    for (int tt = 0; tt < TPW; ++tt) {
        const int m = (t0 + tt) * 16 + mi;
        const float dx = xn - cb[m*3+0];
        const float dy = yn - cb[m*3+1];
        const float dz = zn - cb[m*3+2];
        dv[tt] = __builtin_amdgcn_sqrtf(fmaf(dx, dx, fmaf(dy, dy, dz * dz)));
    }

    const float mu0  = 0.1f * (8 * g);          // segment-start mu
    const float tcst = 0.2f * (8 * g) + 0.1f;   // t_{k0+1} exponent offset
    const float u    = 0.81873075308f;          // e^{-0.2}

    // dense-store permute source lane (validated R8/R10)
    const int srcLane = ((l & 3) << 4) | (l >> 2);
    // lane's dense slot: tile base + l*16B (validated R8/R10)
    float* obase = out + (((size_t)b * NA + n) * NA) * FOUT + l * 4;

    // Phase 2: 6 independent {exp, recurrence, MFMA, permute, store} chains
    #pragma unroll 3
    for (int tt = 0; tt < TPW; ++tt) {
        const int t = t0 + tt;
        const float d  = dv[tt];
        const float dd = d - mu0;
        float r = __expf(-10.0f * dd * dd);     // r_{k0}
        float q = __expf(2.0f * d - tcst);      // ratio t_{k0+1}

        f16x8 bfrag;                            // B[k = 8g+j][m = mi]
        bfrag[0] = (_Float16)r;
        #pragma unroll
        for (int j = 1; j < 8; ++j) {
            r *= q;                             // r_{k0+j}
            q *= u;
            bfrag[j] = (_Float16)r;
        }

        f32x4 acc =                             // D = W * RBF^T + bias
            __builtin_amdgcn_mfma_f32_16x16x32_f16(afrag, bfrag, cinit, 0, 0, 0);

        // permute to lane-dense layout (only lgkm ops in the kernel)
        f32x4 sv;
        sv[0] = __shfl(acc[0], srcLane);
        sv[1] = __shfl(acc[1], srcLane);
        sv[2] = __shfl(acc[2], srcLane);
        sv[3] = __shfl(acc[3], srcLane);

        // dense: lane l stores bytes [l*16, l*16+16) of the tile's 1KB span
        *reinterpret_cast<f32x4*>(obase + (size_t)t * 16 * FOUT) = sv;
    }
}

extern "C" void kernel_launch(void* const* d_in, const int* in_sizes, int n_in,
                              void* d_out, int out_size, void* d_ws, size_t ws_size,
                              hipStream_t stream) {
    const float* coords = (const float*)d_in[0];
    const float* Ww     = (const float*)d_in[1];
    const float* Wb     = (const float*)d_in[2];
    float* out          = (float*)d_out;

    dim3 grid(NA * 2, NB);   // (row-half, b): 6144 blocks, 24576 waves
    cfconv_kernel<<<grid, 256, 0, stream>>>(coords, Ww, Wb, out);
}